// Round 12
// baseline (543.341 us; speedup 1.0000x reference)
//
#include <hip/hip_runtime.h>
#include <hip/hip_fp16.h>

#define N_ATOMS   50000
#define ATOM_FDIM 133
#define HIDDEN    128
#define DEPTH     3
#define N_EDGES   800000
#define N_MOLS    1024
#define BN_EPS    1e-5f
#define K_IN_PAD  160   // 133 padded to 5*32

typedef _Float16 f16x8 __attribute__((ext_vector_type(8)));
typedef _Float16 f16x2 __attribute__((ext_vector_type(2)));
typedef float    f32x4 __attribute__((ext_vector_type(4)));

struct __align__(8) half4pack { __half2 a, b; };

#define HB (N_EDGES / 256)   // 3125 hist blocks
#define FB (N_EDGES / 256)   // 3125 fill blocks
#define GB_IN ((N_ATOMS + 127) / 128)   // 391 gemm blocks

// ---------------- K1: hist (atomic-bound) + conversions (streaming) ----------------
__global__ void hist_conv_kernel(const int* __restrict__ tgt, int* __restrict__ cnt,
                                 const float* __restrict__ f,
                                 const float* __restrict__ W_in,
                                 const float* __restrict__ W1,
                                 const float* __restrict__ W2,
                                 const int* __restrict__ seg,
                                 __half* __restrict__ Ah, __half* __restrict__ Wt,
                                 float* __restrict__ stats, int* __restrict__ moloff)
{
    if (blockIdx.x < HB) {
        int i = blockIdx.x * 256 + threadIdx.x;
        atomicAdd(&cnt[tgt[i]], 1);
        return;
    }
    const int NCH = N_ATOMS * (K_IN_PAD / 4);
    const int NW4 = (128 * K_IN_PAD + 2 * DEPTH * 128 * 128) / 4;
    int i = (blockIdx.x - HB) * 256 + threadIdx.x;
    if (i < NCH) {
        int row = i / (K_IN_PAD / 4);
        int c4  = (i - row * (K_IN_PAD / 4)) * 4;
        float v[4];
        #pragma unroll
        for (int u = 0; u < 4; ++u) {
            int k = c4 + u;
            v[u] = (k < ATOM_FDIM) ? f[(size_t)row * ATOM_FDIM + k] : 0.f;
        }
        half4pack p;
        p.a = __float22half2_rn(make_float2(v[0], v[1]));
        p.b = __float22half2_rn(make_float2(v[2], v[3]));
        *(half4pack*)&Ah[(size_t)row * K_IN_PAD + c4] = p;
        return;
    }
    int j = i - NCH;
    if (j < NW4) {
        float v[4];
        #pragma unroll
        for (int u = 0; u < 4; ++u) {
            int e = j * 4 + u;
            if (e < 128 * K_IN_PAD) {
                int n = e / K_IN_PAD, k = e - n * K_IN_PAD;
                v[u] = (k < ATOM_FDIM) ? W_in[(size_t)k * 128 + n] : 0.f;
            } else if (e < 128 * K_IN_PAD + DEPTH * 128 * 128) {
                int q = e - 128 * K_IN_PAD;
                int d = q >> 14, r = q & 16383;
                int n = r >> 7, k = r & 127;
                v[u] = W1[((size_t)d * 128 + k) * 128 + n];
            } else {
                int q = e - 128 * K_IN_PAD - DEPTH * 128 * 128;
                int d = q >> 14, r = q & 16383;
                int n = r >> 7, k = r & 127;
                v[u] = W2[((size_t)d * 128 + k) * 128 + n];
            }
        }
        half4pack p;
        p.a = __float22half2_rn(make_float2(v[0], v[1]));
        p.b = __float22half2_rn(make_float2(v[2], v[3]));
        *(half4pack*)&Wt[j * 4] = p;
        return;
    }
    int m = j - NW4;
    if (m < DEPTH * 256) stats[m] = 0.f;
    if (m <= N_MOLS) {
        int lo = 0, hi = N_ATOMS;
        while (lo < hi) {
            int mid = (lo + hi) >> 1;
            if (seg[mid] < m) lo = mid + 1; else hi = mid;
        }
        moloff[m] = lo;
    }
}

// ---------------- scan: per-block exclusive scan + bsum ----------------
__global__ void scan_block_kernel(const int* __restrict__ in, int* __restrict__ out,
                                  int* __restrict__ bsum, int n) {
    __shared__ int buf[256];
    int i = blockIdx.x * 256 + threadIdx.x;
    int v = (i < n) ? in[i] : 0;
    buf[threadIdx.x] = v;
    __syncthreads();
    #pragma unroll
    for (int off = 1; off < 256; off <<= 1) {
        int t = (threadIdx.x >= off) ? buf[threadIdx.x - off] : 0;
        __syncthreads();
        buf[threadIdx.x] += t;
        __syncthreads();
    }
    if (i < n) out[i] = buf[threadIdx.x] - v;
    if (threadIdx.x == 255) bsum[blockIdx.x] = buf[255];
}

// scan_add with inline top-scan (nb <= 256): base = sum(bsum[0..blockIdx))
__global__ void scan_add2_kernel(const int* __restrict__ partial, const int* __restrict__ bsum,
                                 int* __restrict__ rowptr, int* __restrict__ wcur,
                                 int n, int total) {
    __shared__ int red[256];
    int v = ((int)threadIdx.x < (int)blockIdx.x) ? bsum[threadIdx.x] : 0;
    red[threadIdx.x] = v;
    __syncthreads();
    #pragma unroll
    for (int o = 128; o > 0; o >>= 1) {
        if (threadIdx.x < o) red[threadIdx.x] += red[threadIdx.x + o];
        __syncthreads();
    }
    int base = red[0];
    int i = blockIdx.x * 256 + threadIdx.x;
    if (i < n) {
        int val = partial[i] + base;
        rowptr[i] = val;
        wcur[i]   = val;
    }
    if (i == 0) rowptr[n] = total;
}

#define LDS_S 40   // padded stride (halves) per 32-half k-chunk row

// ---------------- K4: input-projection MFMA GEMM (blocks [0,GB_IN)) + CSR fill (rest) ----
__global__ __launch_bounds__(256, 2) void gemm_fill_kernel(
    const __half* __restrict__ A, const __half* __restrict__ Bt,
    const float* __restrict__ bias, __half* __restrict__ C, int M, int K,
    const int* __restrict__ src, const int* __restrict__ tgt,
    int* __restrict__ wcur, unsigned short* __restrict__ col)
{
    __shared__ __align__(16) __half As[128 * LDS_S];
    __shared__ __align__(16) __half Bs[128 * LDS_S];

    if (blockIdx.x >= GB_IN) {
        int e = (blockIdx.x - GB_IN) * 256 + threadIdx.x;
        int t = tgt[e];
        int p = atomicAdd(&wcur[t], 1);
        col[p] = (unsigned short)src[e];
        return;
    }

    const int t = threadIdx.x;
    const int w = t >> 6, lane = t & 63;
    const int wm = w >> 1, wn = w & 1;
    const int l15 = lane & 15, quad = lane >> 4;
    const int row0 = blockIdx.x * 128;

    f32x4 acc[4][4];
    #pragma unroll
    for (int mt = 0; mt < 4; ++mt)
        #pragma unroll
        for (int nt = 0; nt < 4; ++nt) acc[mt][nt] = (f32x4){0.f, 0.f, 0.f, 0.f};

    for (int k0 = 0; k0 < K; k0 += 32) {
        #pragma unroll
        for (int i = 0; i < 2; ++i) {
            int c = t * 2 + i;
            int r = c >> 2, o = c & 3;
            int row = row0 + r;
            uint4 v = make_uint4(0, 0, 0, 0);
            if (row < M) v = *(const uint4*)&A[(size_t)row * K + k0 + o * 8];
            *(uint4*)&As[r * LDS_S + o * 8] = v;
        }
        #pragma unroll
        for (int i = 0; i < 2; ++i) {
            int c = t * 2 + i;
            int r = c >> 2, o = c & 3;
            uint4 v = *(const uint4*)&Bt[(size_t)r * K + k0 + o * 8];
            *(uint4*)&Bs[r * LDS_S + o * 8] = v;
        }
        __syncthreads();
        f16x8 af[4], bf[4];
        #pragma unroll
        for (int mt = 0; mt < 4; ++mt)
            af[mt] = *(const f16x8*)&As[(wm * 64 + mt * 16 + l15) * LDS_S + quad * 8];
        #pragma unroll
        for (int nt = 0; nt < 4; ++nt)
            bf[nt] = *(const f16x8*)&Bs[(wn * 64 + nt * 16 + l15) * LDS_S + quad * 8];
        #pragma unroll
        for (int mt = 0; mt < 4; ++mt)
            #pragma unroll
            for (int nt = 0; nt < 4; ++nt)
                acc[mt][nt] = __builtin_amdgcn_mfma_f32_16x16x32_f16(af[mt], bf[nt], acc[mt][nt], 0, 0, 0);
        __syncthreads();
    }

    #pragma unroll
    for (int nt = 0; nt < 4; ++nt) {
        int colc = wn * 64 + nt * 16 + l15;
        float b = bias[colc];
        #pragma unroll
        for (int mt = 0; mt < 4; ++mt) {
            #pragma unroll
            for (int r = 0; r < 4; ++r) {
                int row = row0 + wm * 64 + mt * 16 + quad * 4 + r;
                if (row < M) {
                    float o = fmaxf(acc[mt][nt][r] + b, 0.f);
                    C[(size_t)row * 128 + colc] = __float2half(o);
                }
            }
        }
    }
}

// ---------------- FUSED MLP: hpre = relu(agg@W1+b1)@W2+b2, + BN stats ----------------
__global__ __launch_bounds__(256, 2) void mlp_fused(
    const __half* __restrict__ A, const __half* __restrict__ B1t,
    const __half* __restrict__ B2t,
    const float* __restrict__ bias1, const float* __restrict__ bias2,
    __half* __restrict__ C, int M,
    float* __restrict__ s1, float* __restrict__ s2)
{
    __shared__ __align__(16) __half As[4 * 128 * LDS_S];  // 40 KB
    __shared__ __align__(16) __half Bs[4 * 128 * LDS_S];  // 40 KB

    const int t = threadIdx.x;
    const int w = t >> 6, lane = t & 63;
    const int wm = w >> 1, wn = w & 1;
    const int l15 = lane & 15, quad = lane >> 4;
    const int row0 = blockIdx.x * 128;

    f32x4 acc[4][4];
    #pragma unroll
    for (int mt = 0; mt < 4; ++mt)
        #pragma unroll
        for (int nt = 0; nt < 4; ++nt) acc[mt][nt] = (f32x4){0.f, 0.f, 0.f, 0.f};

    #pragma unroll
    for (int i = 0; i < 8; ++i) {
        int c = i * 256 + t;
        int r = c >> 4, o = c & 15;
        int kc = o >> 2, oo = o & 3;
        int row = row0 + r;
        uint4 v = make_uint4(0, 0, 0, 0);
        if (row < M) v = *(const uint4*)&A[(size_t)row * 128 + o * 8];
        *(uint4*)&As[(kc * 128 + r) * LDS_S + oo * 8] = v;
    }
    #pragma unroll
    for (int i = 0; i < 8; ++i) {
        int c = i * 256 + t;
        int r = c >> 4, o = c & 15;
        int kc = o >> 2, oo = o & 3;
        uint4 v = *(const uint4*)&B1t[(size_t)r * 128 + o * 8];
        *(uint4*)&Bs[(kc * 128 + r) * LDS_S + oo * 8] = v;
    }
    __syncthreads();

    #pragma unroll
    for (int kc = 0; kc < 4; ++kc) {
        f16x8 af[4], bf[4];
        #pragma unroll
        for (int mt = 0; mt < 4; ++mt)
            af[mt] = *(const f16x8*)&As[(kc * 128 + wm * 64 + mt * 16 + l15) * LDS_S + quad * 8];
        #pragma unroll
        for (int nt = 0; nt < 4; ++nt)
            bf[nt] = *(const f16x8*)&Bs[(kc * 128 + wn * 64 + nt * 16 + l15) * LDS_S + quad * 8];
        #pragma unroll
        for (int mt = 0; mt < 4; ++mt)
            #pragma unroll
            for (int nt = 0; nt < 4; ++nt)
                acc[mt][nt] = __builtin_amdgcn_mfma_f32_16x16x32_f16(af[mt], bf[nt], acc[mt][nt], 0, 0, 0);
    }
    __syncthreads();

    #pragma unroll
    for (int nt = 0; nt < 4; ++nt) {
        int k = wn * 64 + nt * 16 + l15;
        float b = bias1[k];
        int kc = k >> 5, ko = k & 31;
        #pragma unroll
        for (int mt = 0; mt < 4; ++mt) {
            #pragma unroll
            for (int r = 0; r < 4; ++r) {
                int rl = wm * 64 + mt * 16 + quad * 4 + r;
                float h = fmaxf(acc[mt][nt][r] + b, 0.f);
                As[(kc * 128 + rl) * LDS_S + ko] = __float2half(h);
            }
        }
    }
    #pragma unroll
    for (int i = 0; i < 8; ++i) {
        int c = i * 256 + t;
        int r = c >> 4, o = c & 15;
        int kc = o >> 2, oo = o & 3;
        uint4 v = *(const uint4*)&B2t[(size_t)r * 128 + o * 8];
        *(uint4*)&Bs[(kc * 128 + r) * LDS_S + oo * 8] = v;
    }
    __syncthreads();

    #pragma unroll
    for (int mt = 0; mt < 4; ++mt)
        #pragma unroll
        for (int nt = 0; nt < 4; ++nt) acc[mt][nt] = (f32x4){0.f, 0.f, 0.f, 0.f};
    #pragma unroll
    for (int kc = 0; kc < 4; ++kc) {
        f16x8 af[4], bf[4];
        #pragma unroll
        for (int mt = 0; mt < 4; ++mt)
            af[mt] = *(const f16x8*)&As[(kc * 128 + wm * 64 + mt * 16 + l15) * LDS_S + quad * 8];
        #pragma unroll
        for (int nt = 0; nt < 4; ++nt)
            bf[nt] = *(const f16x8*)&Bs[(kc * 128 + wn * 64 + nt * 16 + l15) * LDS_S + quad * 8];
        #pragma unroll
        for (int mt = 0; mt < 4; ++mt)
            #pragma unroll
            for (int nt = 0; nt < 4; ++nt)
                acc[mt][nt] = __builtin_amdgcn_mfma_f32_16x16x32_f16(af[mt], bf[nt], acc[mt][nt], 0, 0, 0);
    }

    float ps[4] = {0, 0, 0, 0}, pss[4] = {0, 0, 0, 0};
    #pragma unroll
    for (int nt = 0; nt < 4; ++nt) {
        int col = wn * 64 + nt * 16 + l15;
        float b = bias2[col];
        #pragma unroll
        for (int mt = 0; mt < 4; ++mt) {
            #pragma unroll
            for (int r = 0; r < 4; ++r) {
                int row = row0 + wm * 64 + mt * 16 + quad * 4 + r;
                if (row < M) {
                    float o = acc[mt][nt][r] + b;
                    ps[nt] += o;
                    pss[nt] += o * o;
                    C[(size_t)row * 128 + col] = __float2half(o);
                }
            }
        }
    }

    float* red1 = (float*)As;
    float* red2 = (float*)Bs;
    int contrib = wm * 4 + quad;
    __syncthreads();
    #pragma unroll
    for (int nt = 0; nt < 4; ++nt) {
        int col = wn * 64 + nt * 16 + l15;
        red1[contrib * 128 + col] = ps[nt];
        red2[contrib * 128 + col] = pss[nt];
    }
    __syncthreads();
    if (t < 128) {
        float s = 0.f, q = 0.f;
        #pragma unroll
        for (int g = 0; g < 8; ++g) {
            s += red1[g * 128 + t];
            q += red2[g * 128 + t];
        }
        atomicAdd(&s1[t], s);
        atomicAdd(&s2[t], q);
    }
}

// ---------------- channel-split XCD-affine aggregate ----------------
// 4 channel-groups of 32 ch (64 B = one line per edge-gather). group = (blockIdx&7)>>1.
// Wave = one (atom, group); lanes = 4 edges x 16 channel-pairs; shfl_xor(16,32) reduce.
// TAIL FIX (r11 bug): tail is a predicated loop stepping 4 edges/iter — no edges dropped.
template<bool BN>
__global__ __launch_bounds__(256) void aggregate_cs_kernel(
    const f16x2* __restrict__ xh2, const int* __restrict__ rowptr,
    const unsigned short* __restrict__ col, const float* __restrict__ eps_param, int d,
    const float* __restrict__ s1, const float* __restrict__ s2,
    const float* __restrict__ gamma, const float* __restrict__ beta, int dprev,
    f16x2* __restrict__ aggh2)
{
    const int b = blockIdx.x;
    const int g = (b & 7) >> 1;                    // channel group 0..3
    const int idx = (b >> 3) * 2 + (b & 1);        // 0..12499
    const int wv = threadIdx.x >> 6;
    const int atom = idx * 4 + wv;                 // 0..49999
    const int lane = threadIdx.x & 63;
    const int es = lane >> 4;                      // edge subgroup 0..3
    const int cp = lane & 15;                      // channel pair 0..15
    const int cpg = g * 16 + cp;                   // f16x2 index within row
    const float e1 = 1.0f + eps_param[d];

    float sc_x = 1.f, sc_y = 1.f, c_x = 0.f, c_y = 0.f;
    if (BN) {
        const float inv_n = 1.0f / (float)N_ATOMS;
        int c0 = cpg * 2;
        float m0 = s1[c0] * inv_n;
        float v0 = fmaxf(s2[c0] * inv_n - m0 * m0, 0.f);
        float m1 = s1[c0 + 1] * inv_n;
        float v1 = fmaxf(s2[c0 + 1] * inv_n - m1 * m1, 0.f);
        sc_x = gamma[dprev * 128 + c0]     * rsqrtf(v0 + BN_EPS);
        sc_y = gamma[dprev * 128 + c0 + 1] * rsqrtf(v1 + BN_EPS);
        c_x = beta[dprev * 128 + c0]     / sc_x - m0;
        c_y = beta[dprev * 128 + c0 + 1] / sc_y - m1;
    }

    float2 acc = make_float2(0.f, 0.f);
    const int s = rowptr[atom], e = rowptr[atom + 1];
    int i = s;
    for (; i + 8 <= e; i += 8) {
        int ca = col[i + es];
        int cb = col[i + 4 + es];
        f16x2 va = xh2[(size_t)ca * 64 + cpg];
        f16x2 vb = xh2[(size_t)cb * 64 + cpg];
        float ax = (float)va.x, ay = (float)va.y;
        float bx = (float)vb.x, by = (float)vb.y;
        if (BN) {
            ax = sc_x * fmaxf(ax + c_x, 0.f);
            ay = sc_y * fmaxf(ay + c_y, 0.f);
            bx = sc_x * fmaxf(bx + c_x, 0.f);
            by = sc_y * fmaxf(by + c_y, 0.f);
        }
        acc.x += ax + bx;
        acc.y += ay + by;
    }
    // tail: predicated 4-edge steps (up to 2 iterations) — covers all remaining edges
    for (; i < e; i += 4) {
        int idx2 = i + es;
        int c = col[min(idx2, e - 1)];
        f16x2 v = xh2[(size_t)c * 64 + cpg];
        float fx = (float)v.x, fy = (float)v.y;
        if (BN) {
            fx = sc_x * fmaxf(fx + c_x, 0.f);
            fy = sc_y * fmaxf(fy + c_y, 0.f);
        }
        if (idx2 < e) {
            acc.x += fx;
            acc.y += fy;
        }
    }
    // reduce across the 4 edge subgroups
    acc.x += __shfl_xor(acc.x, 16, 64);
    acc.y += __shfl_xor(acc.y, 16, 64);
    acc.x += __shfl_xor(acc.x, 32, 64);
    acc.y += __shfl_xor(acc.y, 32, 64);

    if (es == 0) {
        f16x2 ah = xh2[(size_t)atom * 64 + cpg];
        float ax = (float)ah.x, ay = (float)ah.y;
        if (BN) {
            ax = sc_x * fmaxf(ax + c_x, 0.f);
            ay = sc_y * fmaxf(ay + c_y, 0.f);
        }
        acc.x += ax * e1;
        acc.y += ay * e1;
        aggh2[(size_t)atom * 64 + cpg] = (f16x2){(_Float16)acc.x, (_Float16)acc.y};
    }
}

// ---------------- per-molecule mean pooling with fused BN+ReLU ----------------
__global__ void pool_kernel(const __half* __restrict__ hh, const int* __restrict__ off,
                            const float* __restrict__ s1, const float* __restrict__ s2,
                            const float* __restrict__ gamma, const float* __restrict__ beta,
                            int dprev, float* __restrict__ out)
{
    int m = blockIdx.x;
    int c = threadIdx.x;
    const float inv_n = 1.0f / (float)N_ATOMS;
    float mean = s1[c] * inv_n;
    float var = fmaxf(s2[c] * inv_n - mean * mean, 0.f);
    float sc = gamma[dprev * 128 + c] * rsqrtf(var + BN_EPS);
    float sh = beta[dprev * 128 + c] - mean * sc;
    int s = off[m], e = off[m + 1];
    float acc = 0.f;
    for (int r = s; r < e; ++r) {
        float v = __half2float(hh[(size_t)r * 128 + c]);
        acc += fmaxf(v * sc + sh, 0.f);
    }
    int cnt = e - s;
    out[m * 128 + c] = (cnt > 0) ? acc / (float)cnt : 0.f;
}

// ---------------- launcher ----------------
extern "C" void kernel_launch(void* const* d_in, const int* in_sizes, int n_in,
                              void* d_out, int out_size, void* d_ws, size_t ws_size,
                              hipStream_t stream)
{
    const float* f_atoms   = (const float*)d_in[0];
    const float* W_in      = (const float*)d_in[1];
    const float* b_in      = (const float*)d_in[2];
    const float* W1        = (const float*)d_in[3];
    const float* b1        = (const float*)d_in[4];
    const float* W2        = (const float*)d_in[5];
    const float* b2        = (const float*)d_in[6];
    const float* gamma     = (const float*)d_in[7];
    const float* beta      = (const float*)d_in[8];
    const float* eps_param = (const float*)d_in[9];
    const int*   edge_index= (const int*)d_in[10];
    const int*   seg       = (const int*)d_in[11];
    const int*   src = edge_index;
    const int*   tgt = edge_index + N_EDGES;
    float* out = (float*)d_out;

    char* ws = (char*)d_ws;
    size_t off = 0;
    auto alloc = [&](size_t bytes) -> char* {
        char* p = ws + off;
        off += (bytes + 255) & ~(size_t)255;
        return p;
    };
    __half* xh    = (__half*)alloc((size_t)N_ATOMS * HIDDEN * 2);   // x0 = relu(proj)
    __half* aggh  = (__half*)alloc((size_t)N_ATOMS * HIDDEN * 2);   // aggregate out
    __half* hpre  = (__half*)alloc((size_t)N_ATOMS * HIDDEN * 2);   // mlp out (pre-BN h)
    __half* Ah    = (__half*)alloc((size_t)N_ATOMS * K_IN_PAD * 2);
    __half* Wt    = (__half*)alloc((size_t)(128 * K_IN_PAD + 2 * DEPTH * 128 * 128) * 2);
    int*   rowptr = (int*)alloc((N_ATOMS + 1) * 4);
    int*   wcur   = (int*)alloc(N_ATOMS * 4);
    int*   partial= (int*)alloc(N_ATOMS * 4);
    int*   bsum   = (int*)alloc(256 * 4);
    unsigned short* col = (unsigned short*)alloc((size_t)N_EDGES * 2);
    float* s12    = (float*)alloc(DEPTH * 256 * 4);
    int*   moloff = (int*)alloc((N_MOLS + 1) * 4);

    const __half* Wt_in = Wt;
    const __half* W1t   = Wt + 128 * K_IN_PAD;
    const __half* W2t   = W1t + DEPTH * 128 * 128;

    // ---- K1: zero wcur, then hist + conversions fused ----
    hipMemsetAsync(wcur, 0, N_ATOMS * 4, stream);
    {
        const int NCH = N_ATOMS * (K_IN_PAD / 4);
        const int NW4 = (128 * K_IN_PAD + 2 * DEPTH * 128 * 128) / 4;
        const int CB  = (NCH + NW4 + N_MOLS + 1 + 255) / 256;
        hist_conv_kernel<<<HB + CB, 256, 0, stream>>>(
            tgt, wcur, f_atoms, W_in, W1, W2, seg, Ah, Wt, s12, moloff);
    }

    // ---- scans ----
    const int NB = (N_ATOMS + 255) / 256;   // 196
    scan_block_kernel<<<NB, 256, 0, stream>>>(wcur, partial, bsum, N_ATOMS);
    scan_add2_kernel<<<NB, 256, 0, stream>>>(partial, bsum, rowptr, wcur, N_ATOMS, N_EDGES);

    // ---- K4: input GEMM + CSR fill fused (gemm blocks first) ----
    gemm_fill_kernel<<<GB_IN + FB, 256, 0, stream>>>(
        Ah, Wt_in, b_in, xh, N_ATOMS, K_IN_PAD, src, tgt, wcur, col);

    for (int d = 0; d < DEPTH; ++d) {
        float* s1d = s12 + d * 256;
        float* s2d = s1d + 128;
        if (d == 0) {
            aggregate_cs_kernel<false><<<N_ATOMS, 256, 0, stream>>>(
                (const f16x2*)xh, rowptr, col, eps_param, d,
                nullptr, nullptr, nullptr, nullptr, 0, (f16x2*)aggh);
        } else {
            float* s1p = s12 + (d - 1) * 256;
            float* s2p = s1p + 128;
            aggregate_cs_kernel<true><<<N_ATOMS, 256, 0, stream>>>(
                (const f16x2*)hpre, rowptr, col, eps_param, d,
                s1p, s2p, gamma, beta, d - 1, (f16x2*)aggh);
        }
        mlp_fused<<<GB_IN, 256, 0, stream>>>(
            aggh, W1t + (size_t)d * 128 * 128, W2t + (size_t)d * 128 * 128,
            b1 + d * HIDDEN, b2 + d * HIDDEN, hpre, N_ATOMS, s1d, s2d);
    }

    pool_kernel<<<N_MOLS, 128, 0, stream>>>(
        hpre, moloff, s12 + (DEPTH - 1) * 256, s12 + (DEPTH - 1) * 256 + 128,
        gamma, beta, DEPTH - 1, out);
}